// Round 1
// baseline (171.027 us; speedup 1.0000x reference)
//
#include <hip/hip_runtime.h>

typedef short short8 __attribute__((ext_vector_type(8)));
typedef float f32x4 __attribute__((ext_vector_type(4)));

#define AS1 __attribute__((address_space(1)))
#define AS3 __attribute__((address_space(3)))

#define NROWS 2048
#define NCOLS 100000
#define NPAD  100352          // 98 chunks * 1024
#define NCHUNK 98
#define K2C 28.853900817779268f   // 20 * log2(e)

__device__ __forceinline__ unsigned short f2bf(float f) {
  unsigned int u = __float_as_uint(f);
  u = u + 0x7FFFu + ((u >> 16) & 1u);   // round to nearest even
  return (unsigned short)(u >> 16);
}

// ---- normalize inputs rows, convert to bf16 ----
__global__ void k_norm(const float* __restrict__ X, unsigned short* __restrict__ Abf) {
  int wid = threadIdx.x >> 6, lane = threadIdx.x & 63;
  int row = blockIdx.x * 4 + wid;
  float2 v = ((const float2*)(X + (size_t)row * 128))[lane];
  float ss = v.x * v.x + v.y * v.y;
#pragma unroll
  for (int m = 1; m < 64; m <<= 1) ss += __shfl_xor(ss, m, 64);
  float inv = 1.0f / fmaxf(sqrtf(ss), 1e-12f);
  ushort2 o;
  o.x = f2bf(v.x * inv);
  o.y = f2bf(v.y * inv);
  ((ushort2*)(Abf + (size_t)row * 128))[lane] = o;
}

// ---- convert features f32 -> bf16, zero-pad rows [100000,100352) ----
__global__ void k_conv(const float* __restrict__ F, unsigned short* __restrict__ Fbf) {
  const int NG = NPAD * 128 / 4;     // 3,211,264 groups of 4
  const int NV = NCOLS * 128 / 4;    // 3,200,000 valid groups
  int stride = gridDim.x * blockDim.x;
  for (int g = blockIdx.x * blockDim.x + threadIdx.x; g < NG; g += stride) {
    float4 v;
    if (g < NV) v = ((const float4*)F)[g];
    else        v = make_float4(0.f, 0.f, 0.f, 0.f);
    ushort4 o;
    o.x = f2bf(v.x); o.y = f2bf(v.y); o.z = f2bf(v.z); o.w = f2bf(v.w);
    ((ushort4*)Fbf)[g] = o;
  }
}

// ---- picked[b] = 20 * dot(normalize(X[b]), F[labels[indexes[b]]])  (exact f32) ----
__global__ void k_picked(const float* __restrict__ X, const int* __restrict__ idx,
                         const int* __restrict__ lab, const float* __restrict__ F,
                         float* __restrict__ picked) {
  int wid = threadIdx.x >> 6, lane = threadIdx.x & 63;
  int row = blockIdx.x * 4 + wid;
  int t = lab[idx[row]];
  float2 v = ((const float2*)(X + (size_t)row * 128))[lane];
  float2 f = ((const float2*)(F + (size_t)t * 128))[lane];
  float ss = v.x * v.x + v.y * v.y;
  float dp = v.x * f.x + v.y * f.y;
#pragma unroll
  for (int m = 1; m < 64; m <<= 1) {
    ss += __shfl_xor(ss, m, 64);
    dp += __shfl_xor(dp, m, 64);
  }
  if (lane == 0) picked[row] = 20.0f * dp / fmaxf(sqrtf(ss), 1e-12f);
}

// ---- fused GEMM + sum of exp(logit - 20) per (row, chunk) ----
// grid = 8 m-tiles * 98 chunks; block = 256 (4 waves, 64 rows each)
__global__ __launch_bounds__(256, 2) void k_gemm(
    const unsigned short* __restrict__ Abf,
    const unsigned short* __restrict__ Fbf,
    float* __restrict__ part) {
  __shared__ unsigned short smem[2][128 * 128];
  const int tid = threadIdx.x;
  const int wid = tid >> 6, lane = tid & 63;
  const int lrow = lane & 15, lk = lane >> 4;
  const int mtile = blockIdx.x & 7;
  const int chunk = blockIdx.x >> 3;
  const int row0 = mtile * 256 + wid * 64;

  // A fragments in registers: af[mf][ks], 16B/lane each
  short8 af[4][4];
#pragma unroll
  for (int mf = 0; mf < 4; ++mf)
#pragma unroll
    for (int ks = 0; ks < 4; ++ks)
      af[mf][ks] = *(const short8*)(Abf + (size_t)(row0 + mf * 16 + lrow) * 128 + (ks * 4 + lk) * 8);

  float racc[4][4];
#pragma unroll
  for (int mf = 0; mf < 4; ++mf)
#pragma unroll
    for (int j = 0; j < 4; ++j) racc[mf][j] = 0.f;

  const int nbase = chunk * 1024;

  // stage step 0 (pre-swizzled source, linear LDS dest)
#pragma unroll
  for (int it = 0; it < 8; ++it) {
    int off16 = it * 256 + tid;
    int nloc = off16 >> 4, ps = off16 & 15;
    int ls = ps ^ (nloc & 7);
    const unsigned short* src = Fbf + (size_t)(nbase + nloc) * 128 + ls * 8;
    __builtin_amdgcn_global_load_lds((const AS1 void*)src,
                                     (AS3 void*)(&smem[0][off16 * 8]), 16, 0, 0);
  }
  __syncthreads();

  int cur = 0;
  for (int t = 0; t < 8; ++t) {
    if (t < 7) {
      int n0 = nbase + (t + 1) * 128;
#pragma unroll
      for (int it = 0; it < 8; ++it) {
        int off16 = it * 256 + tid;
        int nloc = off16 >> 4, ps = off16 & 15;
        int ls = ps ^ (nloc & 7);
        const unsigned short* src = Fbf + (size_t)(n0 + nloc) * 128 + ls * 8;
        __builtin_amdgcn_global_load_lds((const AS1 void*)src,
                                         (AS3 void*)(&smem[cur ^ 1][off16 * 8]), 16, 0, 0);
      }
    }
    const unsigned short* sb = &smem[cur][0];
    // two 64-col halves to keep acc at 64 VGPRs
#pragma unroll
    for (int h = 0; h < 2; ++h) {
      f32x4 acc[4][4];
#pragma unroll
      for (int mf = 0; mf < 4; ++mf)
#pragma unroll
        for (int nf = 0; nf < 4; ++nf) acc[mf][nf] = (f32x4){0.f, 0.f, 0.f, 0.f};
#pragma unroll
      for (int ks = 0; ks < 4; ++ks) {
        short8 bf[4];
#pragma unroll
        for (int nf = 0; nf < 4; ++nf) {
          int nloc = (h * 4 + nf) * 16 + lrow;
          int phys = (ks * 4 + lk) ^ (nloc & 7);
          bf[nf] = *(const short8*)(sb + nloc * 128 + phys * 8);
        }
#pragma unroll
        for (int mf = 0; mf < 4; ++mf)
#pragma unroll
          for (int nf = 0; nf < 4; ++nf)
            acc[mf][nf] = __builtin_amdgcn_mfma_f32_16x16x32_bf16(
                af[mf][ks], bf[nf], acc[mf][nf], 0, 0, 0);
      }
      // exp(logit - 20) = exp2((dot - 1) * 20*log2e), accumulate per row
#pragma unroll
      for (int mf = 0; mf < 4; ++mf)
#pragma unroll
        for (int j = 0; j < 4; ++j) {
          float s = 0.f;
#pragma unroll
          for (int nf = 0; nf < 4; ++nf)
            s += __builtin_amdgcn_exp2f(fmaf(acc[mf][nf][j], K2C, -K2C));
          racc[mf][j] += s;
        }
    }
    __syncthreads();
    cur ^= 1;
  }

  // reduce partial row-sums across the 16 lanes sharing each row, write out
#pragma unroll
  for (int mf = 0; mf < 4; ++mf)
#pragma unroll
    for (int j = 0; j < 4; ++j) {
      float v = racc[mf][j];
      v += __shfl_xor(v, 1, 64);
      v += __shfl_xor(v, 2, 64);
      v += __shfl_xor(v, 4, 64);
      v += __shfl_xor(v, 8, 64);
      if (lrow == 0) {
        int row = row0 + mf * 16 + lk * 4 + j;
        part[(size_t)chunk * NROWS + row] = v;
      }
    }
}

// ---- per-row loss, block partial sums ----
__global__ void k_loss(const float* __restrict__ part, const float* __restrict__ picked,
                       float* __restrict__ bsum) {
  int tid = threadIdx.x;
  int b = blockIdx.x * 256 + tid;
  float tot = 0.f;
  for (int c = 0; c < NCHUNK; ++c) tot += part[(size_t)c * NROWS + b];
  float lb = 20.0f + logf(tot) - picked[b];
#pragma unroll
  for (int m = 1; m < 64; m <<= 1) lb += __shfl_xor(lb, m, 64);
  __shared__ float red[4];
  if ((tid & 63) == 0) red[tid >> 6] = lb;
  __syncthreads();
  if (tid == 0) bsum[blockIdx.x] = red[0] + red[1] + red[2] + red[3];
}

__global__ void k_final(const float* __restrict__ bsum, float* __restrict__ out) {
  if (threadIdx.x == 0) {
    float s = 0.f;
#pragma unroll
    for (int i = 0; i < 8; ++i) s += bsum[i];
    out[0] = s * (1.0f / 2048.0f);
  }
}

extern "C" void kernel_launch(void* const* d_in, const int* in_sizes, int n_in,
                              void* d_out, int out_size, void* d_ws, size_t ws_size,
                              hipStream_t stream) {
  const float* inputs  = (const float*)d_in[0];
  const int*   indexes = (const int*)d_in[1];
  const int*   labels  = (const int*)d_in[2];
  const float* feats   = (const float*)d_in[3];
  float* out = (float*)d_out;

  char* ws = (char*)d_ws;
  unsigned short* Abf = (unsigned short*)(ws + 0);            // 2048*128*2   = 524,288
  unsigned short* Fbf = (unsigned short*)(ws + 524288);       // 100352*128*2 = 25,690,112
  float* part   = (float*)(ws + 26214400);                    // 98*2048*4    = 802,816
  float* picked = (float*)(ws + 27017216);                    // 2048*4
  float* bsum   = (float*)(ws + 27025408);                    // 8*4

  hipLaunchKernelGGL(k_norm,   dim3(512),  dim3(256), 0, stream, inputs, Abf);
  hipLaunchKernelGGL(k_conv,   dim3(2048), dim3(256), 0, stream, feats, Fbf);
  hipLaunchKernelGGL(k_picked, dim3(512),  dim3(256), 0, stream, inputs, indexes, labels, feats, picked);
  hipLaunchKernelGGL(k_gemm,   dim3(8 * NCHUNK), dim3(256), 0, stream, Abf, Fbf, part);
  hipLaunchKernelGGL(k_loss,   dim3(8),    dim3(256), 0, stream, part, picked, bsum);
  hipLaunchKernelGGL(k_final,  dim3(1),    dim3(64),  0, stream, bsum, out);
}